// Round 5
// baseline (71.895 us; speedup 1.0000x reference)
//
#include <hip/hip_runtime.h>
#include <hip/hip_bf16.h>
#include <stdint.h>

#define NS 8192
#define NHALF 4096
#define DIM 256
#define BLK 128
#define BK 64
#define NKT (DIM / BK)           // 4 K-steps
#define NTILES (NS / BLK)        // 64
#define HALF_TILES (NHALF / BLK) // 32
#define NTRI (NTILES * (NTILES + 1) / 2)  // 2080 upper-tri tiles
#define PREP_BLOCKS 256

typedef __attribute__((ext_vector_type(8))) short bf16x8;
typedef __attribute__((ext_vector_type(4))) float f32x4;
typedef __attribute__((ext_vector_type(8))) unsigned short u16x8;

// workspace layout (bytes) — round-0 proven layout
#define XB_OFF   0                         // bf16 X: 8192*256*2 = 4 MiB
#define SQ_OFF   (NS * DIM * 2)            // f32 sq[8192] = 32 KiB
#define PART_OFF (SQ_OFF + NS * 4)         // f32 partials[256][256] = 256 KiB
#define ACC_OFF  (PART_OFF + PREP_BLOCKS * DIM * 4)  // f64 signed kernel sum
#define C0_OFF   (ACC_OFF + 8)             // f32 log2e / bandwidth
#define WS_NEED  (C0_OFF + 16)

__device__ __forceinline__ unsigned short f2bf(float f) {
  unsigned int u = __float_as_uint(f);
  u += 0x7fffu + ((u >> 16) & 1u);   // round-to-nearest-even
  return (unsigned short)(u >> 16);
}
__device__ __forceinline__ float bf2f(unsigned short h) {
  return __uint_as_float(((unsigned int)h) << 16);
}

// ---- Kernel 1: convert to bf16, row ||x||^2, per-block column partials ----
// (round-0 exact)
__global__ __launch_bounds__(256) void mmd_prep(
    const float* __restrict__ src, const float* __restrict__ tgt,
    unsigned short* __restrict__ Xb, float* __restrict__ sq,
    float* __restrict__ partials) {
  int tid = threadIdx.x;
  int lane32 = tid & 31;
  int rgrp = tid >> 5;
  int c = lane32 * 8;
  int rowBase = blockIdx.x * 32;

  float colpart[8];
#pragma unroll
  for (int j = 0; j < 8; ++j) colpart[j] = 0.f;

#pragma unroll
  for (int p = 0; p < 4; ++p) {
    int row = rowBase + p * 8 + rgrp;
    const float* X = (row < NHALF) ? (src + (size_t)row * DIM)
                                   : (tgt + (size_t)(row - NHALF) * DIM);
    float4 v0 = *(const float4*)(X + c);
    float4 v1 = *(const float4*)(X + c + 4);
    float vals[8] = {v0.x, v0.y, v0.z, v0.w, v1.x, v1.y, v1.z, v1.w};
    u16x8 h;
    float s = 0.f;
#pragma unroll
    for (int j = 0; j < 8; ++j) {
      unsigned short b = f2bf(vals[j]);
      h[j] = b;
      float rb = bf2f(b);
      s += rb * rb;
      colpart[j] += rb;
    }
    *(u16x8*)(Xb + (size_t)row * DIM + c) = h;
    for (int o = 16; o > 0; o >>= 1) s += __shfl_down(s, o, 32);
    if (lane32 == 0) sq[row] = s;
  }

  __shared__ float cp[8][DIM];
  *(float4*)&cp[rgrp][c]     = make_float4(colpart[0], colpart[1], colpart[2], colpart[3]);
  *(float4*)&cp[rgrp][c + 4] = make_float4(colpart[4], colpart[5], colpart[6], colpart[7]);
  __syncthreads();
  float s8 = 0.f;
#pragma unroll
  for (int r = 0; r < 8; ++r) s8 += cp[r][tid];
  partials[blockIdx.x * DIM + tid] = s8;
}

// ---- Kernel 2: reduce partials + sq -> bandwidth -> c0 (round-0 exact) ----
__global__ __launch_bounds__(256) void mmd_band(
    const float* __restrict__ partials, const float* __restrict__ sq,
    float* __restrict__ c0out) {
  __shared__ double buf2[DIM];
  __shared__ float buf1[DIM];
  int tid = threadIdx.x;
  float cs = 0.f;
  for (int b = 0; b < PREP_BLOCKS; ++b) cs += partials[b * DIM + tid];
  float s1 = 0.f;
  for (int k = 0; k < NS / DIM; ++k) s1 += sq[k * DIM + tid];
  buf2[tid] = (double)cs * (double)cs;
  buf1[tid] = s1;
  __syncthreads();
  for (int o = 128; o > 0; o >>= 1) {
    if (tid < o) { buf2[tid] += buf2[tid + o]; buf1[tid] += buf1[tid + o]; }
    __syncthreads();
  }
  if (tid == 0) {
    double S1 = (double)buf1[0];
    double S2 = buf2[0];
    double sum_l2 = 2.0 * (double)NS * S1 - 2.0 * S2;
    double bw = sum_l2 / ((double)NS * (double)NS - (double)NS);
    bw = bw / 4.0;
    c0out[0] = (float)(1.4426950408889634 / bw);
  }
}

// ---- Kernel 3: 128x128 Gram tile, 2-phase double-buffered staging ----
// LDS is EXACTLY 64 KiB (2x16K A + 2x16K B; the cross-wave reduce reuses As
// after the K-loop) so two blocks fit a 128-KiB pool — round 4's extra
// red4[4] pushed LDS_Block_Size to 66048 and dropped residency to 1 block/CU.
// Epilogue sq/c0 loads are hoisted ABOVE the K-loop: their L2 latency is
// hidden under ~25K cycles of MFMA instead of exposed in the post-barrier tail.
#define STAGE(KT, BUF)                                                        \
  {                                                                           \
    _Pragma("unroll") for (int it = 0; it < 4; ++it) {                        \
      int idx = it * 256 + tid;                                               \
      int r = idx >> 3, g = idx & 7, gs = g ^ (r & 7);                        \
      const unsigned short* ga =                                              \
          Xb + (size_t)(rowBase + r) * DIM + (KT)*BK + gs * 8;                \
      __builtin_amdgcn_global_load_lds(                                       \
          (const __attribute__((address_space(1))) void*)ga,                  \
          (__attribute__((address_space(3))) void*)(&As[BUF][idx * 8]), 16,   \
          0, 0);                                                              \
      const unsigned short* gb =                                              \
          Xb + (size_t)(colBase + r) * DIM + (KT)*BK + gs * 8;                \
      __builtin_amdgcn_global_load_lds(                                       \
          (const __attribute__((address_space(1))) void*)gb,                  \
          (__attribute__((address_space(3))) void*)(&Bs[BUF][idx * 8]), 16,   \
          0, 0);                                                              \
    }                                                                         \
  }

__global__ __launch_bounds__(256, 2) void mmd_gram(
    const unsigned short* __restrict__ Xb, const float* __restrict__ sq,
    const float* __restrict__ c0p, double* __restrict__ accK) {
  int l = blockIdx.x;
  int bj = (int)((sqrtf(8.f * (float)l + 1.f) - 1.f) * 0.5f);
  while ((bj + 1) * (bj + 2) / 2 <= l) bj++;
  while (bj * (bj + 1) / 2 > l) bj--;
  int bi = l - bj * (bj + 1) / 2;

  __shared__ __align__(16) unsigned short As[2][BLK * BK];  // 32 KiB
  __shared__ __align__(16) unsigned short Bs[2][BLK * BK];  // 32 KiB
  int tid = threadIdx.x;
  int wave = tid >> 6;
  int lane = tid & 63;
  int rowBase = bi * BLK, colBase = bj * BLK;
  int wr = (wave >> 1) * 64;   // wave's 64x64 quadrant
  int wc = (wave & 1) * 64;

  // hoisted epilogue constants: loads issue now, consumed after the K-loop
  float c0 = *c0p;
  float cE = -0.0625f * c0;      // arg = cE*(sqr+sqc) + t2*acc
  float t2 = -2.f * cE;
  float a_[4][4], b_[4];
  int r4 = (lane >> 4) * 4;
#pragma unroll
  for (int m = 0; m < 4; ++m)
#pragma unroll
    for (int r = 0; r < 4; ++r)
      a_[m][r] = cE * sq[rowBase + wr + m * 16 + r4 + r];
#pragma unroll
  for (int n = 0; n < 4; ++n)
    b_[n] = cE * sq[colBase + wc + n * 16 + (lane & 15)];

  f32x4 acc[4][4];
#pragma unroll
  for (int m = 0; m < 4; ++m)
#pragma unroll
    for (int n = 0; n < 4; ++n) acc[m][n] = (f32x4){0.f, 0.f, 0.f, 0.f};

  // prologue: stage K-step 0 into buffer 0 (latency exposed once)
  STAGE(0, 0);
  __syncthreads();

#pragma unroll
  for (int kt = 0; kt < NKT; ++kt) {
    int cur = kt & 1;
    if (kt < NKT - 1) STAGE(kt + 1, cur ^ 1);   // prefetch next tile

#pragma unroll
    for (int ks = 0; ks < 2; ++ks) {
      bf16x8 af[4], bfr[4];
      int kg = ks * 4 + (lane >> 4);   // 16B group index of this lane's k-slice
#pragma unroll
      for (int m = 0; m < 4; ++m) {
        int r = wr + m * 16 + (lane & 15);
        af[m] = *(const bf16x8*)(&As[cur][r * BK + (kg ^ (r & 7)) * 8]);
      }
#pragma unroll
      for (int n = 0; n < 4; ++n) {
        int r = wc + n * 16 + (lane & 15);
        bfr[n] = *(const bf16x8*)(&Bs[cur][r * BK + (kg ^ (r & 7)) * 8]);
      }
#pragma unroll
      for (int m = 0; m < 4; ++m)
#pragma unroll
        for (int n = 0; n < 4; ++n)
          acc[m][n] = __builtin_amdgcn_mfma_f32_16x16x32_bf16(
              af[m], bfr[n], acc[m][n], 0, 0, 0);
    }
    // drains vmcnt(0) (prefetch had full compute phase to land) + barrier:
    // all waves done reading buf[cur] -> safe to overwrite next iteration.
    __syncthreads();
  }

  // ---- epilogue: l2 -> sum of 5 Gaussians (1 exp2 + 4 squarings) ----
  float tsum = 0.f;
#pragma unroll
  for (int m = 0; m < 4; ++m)
#pragma unroll
    for (int n = 0; n < 4; ++n)
#pragma unroll
      for (int r = 0; r < 4; ++r) {
        // C/D layout (m89): col = lane&15, row = (lane>>4)*4 + reg
        float arg = fmaf(acc[m][n][r], t2, a_[m][r] + b_[n]);
        float e4 = exp2f(arg);           // e_{k-1} = e_k^2
        float e3 = e4 * e4;
        float e2 = e3 * e3;
        float e1 = e2 * e2;
        float e0 = e1 * e1;
        tsum += ((e4 + e3) + (e2 + e1)) + e0;
      }

  // wave-level shuffle reduce (6 ops), then tiny cross-wave combine.
  // As is dead after the K-loop's final barrier -> reuse as reduce scratch
  // (keeps total LDS at exactly 65536 B so 2 blocks/CU fit).
  float* red4 = (float*)&As[0][0];
#pragma unroll
  for (int o = 32; o > 0; o >>= 1) tsum += __shfl_down(tsum, o);
  if (lane == 0) red4[wave] = tsum;
  __syncthreads();
  if (tid == 0) {
    float t = (red4[0] + red4[1]) + (red4[2] + red4[3]);
    float sign = ((bi < HALF_TILES) == (bj < HALF_TILES)) ? 1.f : -1.f;
    float factor = (bi == bj) ? sign : 2.f * sign;  // off-diag tiles doubled
    atomicAdd(accK, (double)(factor * t));
  }
}

// ---- Kernel 4: finalize (round-0 exact) ----
__global__ void mmd_final(const double* __restrict__ accK, float* __restrict__ out) {
  out[0] = (float)(accK[0] / ((double)NHALF * (double)NHALF));
}

extern "C" void kernel_launch(void* const* d_in, const int* in_sizes, int n_in,
                              void* d_out, int out_size, void* d_ws, size_t ws_size,
                              hipStream_t stream) {
  if (ws_size < (size_t)WS_NEED) return;  // need ~4.3 MiB scratch
  const float* src = (const float*)d_in[0];
  const float* tgt = (const float*)d_in[1];
  char* ws = (char*)d_ws;
  unsigned short* Xb = (unsigned short*)(ws + XB_OFF);
  float* sq          = (float*)(ws + SQ_OFF);
  float* partials    = (float*)(ws + PART_OFF);
  double* accK       = (double*)(ws + ACC_OFF);
  float* c0          = (float*)(ws + C0_OFF);

  hipMemsetAsync(ws + ACC_OFF, 0, 16, stream);  // accK only
  mmd_prep<<<PREP_BLOCKS, 256, 0, stream>>>(src, tgt, Xb, sq, partials);
  mmd_band<<<1, 256, 0, stream>>>(partials, sq, c0);
  mmd_gram<<<NTRI, 256, 0, stream>>>(Xb, sq, c0, accK);
  mmd_final<<<1, 1, 0, stream>>>(accK, (float*)d_out);
}

// Round 6
// 71.177 us; speedup vs baseline: 1.0101x; 1.0101x over previous
//
#include <hip/hip_runtime.h>
#include <hip/hip_bf16.h>
#include <stdint.h>

#define NS 8192
#define NHALF 4096
#define DIM 256
#define BLK 128
#define BK 32
#define NKT (DIM / BK)           // 8 K-steps
#define NTILES (NS / BLK)        // 64
#define HALF_TILES (NHALF / BLK) // 32
#define NTRI (NTILES * (NTILES + 1) / 2)  // 2080 upper-tri tiles
#define PREP_BLOCKS 256

typedef __attribute__((ext_vector_type(8))) short bf16x8;
typedef __attribute__((ext_vector_type(4))) float f32x4;
typedef __attribute__((ext_vector_type(8))) unsigned short u16x8;

// workspace layout (bytes) — round-0 proven layout
#define XB_OFF   0                         // bf16 X: 8192*256*2 = 4 MiB
#define SQ_OFF   (NS * DIM * 2)            // f32 sq[8192] = 32 KiB
#define PART_OFF (SQ_OFF + NS * 4)         // f32 partials[256][256] = 256 KiB
#define ACC_OFF  (PART_OFF + PREP_BLOCKS * DIM * 4)  // f64 signed kernel sum
#define C0_OFF   (ACC_OFF + 8)             // f32 log2e / bandwidth
#define WS_NEED  (C0_OFF + 16)

__device__ __forceinline__ unsigned short f2bf(float f) {
  unsigned int u = __float_as_uint(f);
  u += 0x7fffu + ((u >> 16) & 1u);   // round-to-nearest-even
  return (unsigned short)(u >> 16);
}
__device__ __forceinline__ float bf2f(unsigned short h) {
  return __uint_as_float(((unsigned int)h) << 16);
}

// ---- Kernel 1: convert to bf16, row ||x||^2, per-block column partials ----
// (round-0 exact)
__global__ __launch_bounds__(256) void mmd_prep(
    const float* __restrict__ src, const float* __restrict__ tgt,
    unsigned short* __restrict__ Xb, float* __restrict__ sq,
    float* __restrict__ partials) {
  int tid = threadIdx.x;
  int lane32 = tid & 31;
  int rgrp = tid >> 5;
  int c = lane32 * 8;
  int rowBase = blockIdx.x * 32;

  float colpart[8];
#pragma unroll
  for (int j = 0; j < 8; ++j) colpart[j] = 0.f;

#pragma unroll
  for (int p = 0; p < 4; ++p) {
    int row = rowBase + p * 8 + rgrp;
    const float* X = (row < NHALF) ? (src + (size_t)row * DIM)
                                   : (tgt + (size_t)(row - NHALF) * DIM);
    float4 v0 = *(const float4*)(X + c);
    float4 v1 = *(const float4*)(X + c + 4);
    float vals[8] = {v0.x, v0.y, v0.z, v0.w, v1.x, v1.y, v1.z, v1.w};
    u16x8 h;
    float s = 0.f;
#pragma unroll
    for (int j = 0; j < 8; ++j) {
      unsigned short b = f2bf(vals[j]);
      h[j] = b;
      float rb = bf2f(b);
      s += rb * rb;
      colpart[j] += rb;
    }
    *(u16x8*)(Xb + (size_t)row * DIM + c) = h;
    for (int o = 16; o > 0; o >>= 1) s += __shfl_down(s, o, 32);
    if (lane32 == 0) sq[row] = s;
  }

  __shared__ float cp[8][DIM];
  *(float4*)&cp[rgrp][c]     = make_float4(colpart[0], colpart[1], colpart[2], colpart[3]);
  *(float4*)&cp[rgrp][c + 4] = make_float4(colpart[4], colpart[5], colpart[6], colpart[7]);
  __syncthreads();
  float s8 = 0.f;
#pragma unroll
  for (int r = 0; r < 8; ++r) s8 += cp[r][tid];
  partials[blockIdx.x * DIM + tid] = s8;
}

// ---- Kernel 2: reduce partials + sq -> bandwidth -> c0 (round-0 exact) ----
__global__ __launch_bounds__(256) void mmd_band(
    const float* __restrict__ partials, const float* __restrict__ sq,
    float* __restrict__ c0out) {
  __shared__ double buf2[DIM];
  __shared__ float buf1[DIM];
  int tid = threadIdx.x;
  float cs = 0.f;
  for (int b = 0; b < PREP_BLOCKS; ++b) cs += partials[b * DIM + tid];
  float s1 = 0.f;
  for (int k = 0; k < NS / DIM; ++k) s1 += sq[k * DIM + tid];
  buf2[tid] = (double)cs * (double)cs;
  buf1[tid] = s1;
  __syncthreads();
  for (int o = 128; o > 0; o >>= 1) {
    if (tid < o) { buf2[tid] += buf2[tid + o]; buf1[tid] += buf1[tid + o]; }
    __syncthreads();
  }
  if (tid == 0) {
    double S1 = (double)buf1[0];
    double S2 = buf2[0];
    double sum_l2 = 2.0 * (double)NS * S1 - 2.0 * S2;
    double bw = sum_l2 / ((double)NS * (double)NS - (double)NS);
    bw = bw / 4.0;
    c0out[0] = (float)(1.4426950408889634 / bw);
  }
}

// ---- Kernel 3: 128x128 Gram tile, BK=32 double-buffered staging ----
// r5 lesson: 64-KiB-LDS blocks never co-reside (pool < 131072 usable), so
// dbuf at BK=64 forced 1 block/CU. BK=32 keeps dbuf at 32768 B total ->
// 4 blocks/CU, same staging-bytes-per-MAC, VGPR unchanged.
// Swizzle for 64-B rows: gs = g ^ ((r>>1)&3). Within a 16-lane column group,
// rows 0..7 hit 8 distinct bank-quads (gs flips every 2 rows; row parity
// supplies bank bit 4); rows 8..15 repeat -> 2-way conflict = free (m136).
// Same involution on pre-swizzled global source and LDS read (rule #21).
#define STAGE(KT, BUF)                                                        \
  {                                                                           \
    _Pragma("unroll") for (int it = 0; it < 2; ++it) {                        \
      int idx = it * 256 + tid;            /* 0..511, 16B each */             \
      int r = idx >> 2, g = idx & 3;       /* row 0..127, 16B group 0..3 */   \
      int gs = g ^ ((r >> 1) & 3);                                            \
      const unsigned short* ga =                                              \
          Xb + (size_t)(rowBase + r) * DIM + (KT)*BK + gs * 8;                \
      __builtin_amdgcn_global_load_lds(                                       \
          (const __attribute__((address_space(1))) void*)ga,                  \
          (__attribute__((address_space(3))) void*)(&As[BUF][idx * 8]), 16,   \
          0, 0);                                                              \
      const unsigned short* gb =                                              \
          Xb + (size_t)(colBase + r) * DIM + (KT)*BK + gs * 8;                \
      __builtin_amdgcn_global_load_lds(                                       \
          (const __attribute__((address_space(1))) void*)gb,                  \
          (__attribute__((address_space(3))) void*)(&Bs[BUF][idx * 8]), 16,   \
          0, 0);                                                              \
    }                                                                         \
  }

__global__ __launch_bounds__(256, 2) void mmd_gram(
    const unsigned short* __restrict__ Xb, const float* __restrict__ sq,
    const float* __restrict__ c0p, double* __restrict__ accK) {
  int l = blockIdx.x;
  int bj = (int)((sqrtf(8.f * (float)l + 1.f) - 1.f) * 0.5f);
  while ((bj + 1) * (bj + 2) / 2 <= l) bj++;
  while (bj * (bj + 1) / 2 > l) bj--;
  int bi = l - bj * (bj + 1) / 2;

  __shared__ __align__(16) unsigned short As[2][BLK * BK];  // 16 KiB
  __shared__ __align__(16) unsigned short Bs[2][BLK * BK];  // 16 KiB
  int tid = threadIdx.x;
  int wave = tid >> 6;
  int lane = tid & 63;
  int rowBase = bi * BLK, colBase = bj * BLK;
  int wr = (wave >> 1) * 64;   // wave's 64x64 quadrant
  int wc = (wave & 1) * 64;

  // hoisted epilogue constants: loads issue now, consumed after the K-loop
  float c0 = *c0p;
  float cE = -0.0625f * c0;      // arg = cE*(sqr+sqc) + t2*acc
  float t2 = -2.f * cE;
  float a_[4][4], b_[4];
  int r4 = (lane >> 4) * 4;
#pragma unroll
  for (int m = 0; m < 4; ++m)
#pragma unroll
    for (int r = 0; r < 4; ++r)
      a_[m][r] = cE * sq[rowBase + wr + m * 16 + r4 + r];
#pragma unroll
  for (int n = 0; n < 4; ++n)
    b_[n] = cE * sq[colBase + wc + n * 16 + (lane & 15)];

  f32x4 acc[4][4];
#pragma unroll
  for (int m = 0; m < 4; ++m)
#pragma unroll
    for (int n = 0; n < 4; ++n) acc[m][n] = (f32x4){0.f, 0.f, 0.f, 0.f};

  // prologue: stage K-step 0 into buffer 0 (latency exposed once)
  STAGE(0, 0);
  __syncthreads();

#pragma unroll
  for (int kt = 0; kt < NKT; ++kt) {
    int cur = kt & 1;
    if (kt < NKT - 1) STAGE(kt + 1, cur ^ 1);   // prefetch next K-step

    bf16x8 af[4], bfr[4];
    int kg = lane >> 4;              // 16B k-group 0..3 of this lane
#pragma unroll
    for (int m = 0; m < 4; ++m) {
      int r = wr + m * 16 + (lane & 15);
      af[m] = *(const bf16x8*)(&As[cur][r * BK + (kg ^ ((r >> 1) & 3)) * 8]);
    }
#pragma unroll
    for (int n = 0; n < 4; ++n) {
      int r = wc + n * 16 + (lane & 15);
      bfr[n] = *(const bf16x8*)(&Bs[cur][r * BK + (kg ^ ((r >> 1) & 3)) * 8]);
    }
#pragma unroll
    for (int m = 0; m < 4; ++m)
#pragma unroll
      for (int n = 0; n < 4; ++n)
        acc[m][n] = __builtin_amdgcn_mfma_f32_16x16x32_bf16(
            af[m], bfr[n], acc[m][n], 0, 0, 0);

    // drains vmcnt(0) (prefetch had the compute phase + TLP to land) +
    // barrier: all waves done reading buf[cur] -> safe to overwrite.
    __syncthreads();
  }

  // ---- epilogue: l2 -> sum of 5 Gaussians (1 exp2 + 4 squarings) ----
  float tsum = 0.f;
#pragma unroll
  for (int m = 0; m < 4; ++m)
#pragma unroll
    for (int n = 0; n < 4; ++n)
#pragma unroll
      for (int r = 0; r < 4; ++r) {
        // C/D layout (m89): col = lane&15, row = (lane>>4)*4 + reg
        float arg = fmaf(acc[m][n][r], t2, a_[m][r] + b_[n]);
        float e4 = exp2f(arg);           // e_{k-1} = e_k^2
        float e3 = e4 * e4;
        float e2 = e3 * e3;
        float e1 = e2 * e2;
        float e0 = e1 * e1;
        tsum += ((e4 + e3) + (e2 + e1)) + e0;
      }

  // wave-level shuffle reduce (6 ops), then tiny cross-wave combine.
  // As is dead after the K-loop's final barrier -> reuse as reduce scratch
  // (keeps total LDS at exactly 32768 B).
  float* red4 = (float*)&As[0][0];
#pragma unroll
  for (int o = 32; o > 0; o >>= 1) tsum += __shfl_down(tsum, o);
  if (lane == 0) red4[wave] = tsum;
  __syncthreads();
  if (tid == 0) {
    float t = (red4[0] + red4[1]) + (red4[2] + red4[3]);
    float sign = ((bi < HALF_TILES) == (bj < HALF_TILES)) ? 1.f : -1.f;
    float factor = (bi == bj) ? sign : 2.f * sign;  // off-diag tiles doubled
    atomicAdd(accK, (double)(factor * t));
  }
}

// ---- Kernel 4: finalize (round-0 exact) ----
__global__ void mmd_final(const double* __restrict__ accK, float* __restrict__ out) {
  out[0] = (float)(accK[0] / ((double)NHALF * (double)NHALF));
}

extern "C" void kernel_launch(void* const* d_in, const int* in_sizes, int n_in,
                              void* d_out, int out_size, void* d_ws, size_t ws_size,
                              hipStream_t stream) {
  if (ws_size < (size_t)WS_NEED) return;  // need ~4.3 MiB scratch
  const float* src = (const float*)d_in[0];
  const float* tgt = (const float*)d_in[1];
  char* ws = (char*)d_ws;
  unsigned short* Xb = (unsigned short*)(ws + XB_OFF);
  float* sq          = (float*)(ws + SQ_OFF);
  float* partials    = (float*)(ws + PART_OFF);
  double* accK       = (double*)(ws + ACC_OFF);
  float* c0          = (float*)(ws + C0_OFF);

  hipMemsetAsync(ws + ACC_OFF, 0, 16, stream);  // accK only
  mmd_prep<<<PREP_BLOCKS, 256, 0, stream>>>(src, tgt, Xb, sq, partials);
  mmd_band<<<1, 256, 0, stream>>>(partials, sq, c0);
  mmd_gram<<<NTRI, 256, 0, stream>>>(Xb, sq, c0, accK);
  mmd_final<<<1, 1, 0, stream>>>(accK, (float*)d_out);
}

// Round 7
// 68.222 us; speedup vs baseline: 1.0538x; 1.0433x over previous
//
#include <hip/hip_runtime.h>
#include <hip/hip_bf16.h>
#include <stdint.h>

#define NS 8192
#define NHALF 4096
#define DIM 256
#define BLK 128
#define BK 32
#define NKT (DIM / BK)           // 8 K-steps
#define NTILES (NS / BLK)        // 64
#define HALF_TILES (NHALF / BLK) // 32
#define NTRI (NTILES * (NTILES + 1) / 2)  // 2080 upper-tri tiles
#define PREP_BLOCKS 256

typedef __attribute__((ext_vector_type(8))) short bf16x8;
typedef __attribute__((ext_vector_type(4))) float f32x4;
typedef __attribute__((ext_vector_type(8))) unsigned short u16x8;

// workspace layout (bytes) — round-0 proven layout
#define XB_OFF   0                         // bf16 X: 8192*256*2 = 4 MiB
#define SQ_OFF   (NS * DIM * 2)            // f32 sq[8192] = 32 KiB
#define PART_OFF (SQ_OFF + NS * 4)         // f32 partials[256][256] = 256 KiB
#define ACC_OFF  (PART_OFF + PREP_BLOCKS * DIM * 4)  // f64 signed kernel sum
#define C0_OFF   (ACC_OFF + 8)             // f32 log2e / bandwidth
#define WS_NEED  (C0_OFF + 16)

__device__ __forceinline__ unsigned short f2bf(float f) {
  unsigned int u = __float_as_uint(f);
  u += 0x7fffu + ((u >> 16) & 1u);   // round-to-nearest-even
  return (unsigned short)(u >> 16);
}
__device__ __forceinline__ float bf2f(unsigned short h) {
  return __uint_as_float(((unsigned int)h) << 16);
}

// ---- Kernel 1: convert to bf16, row ||x||^2, per-block column partials ----
// (round-0 exact)
__global__ __launch_bounds__(256) void mmd_prep(
    const float* __restrict__ src, const float* __restrict__ tgt,
    unsigned short* __restrict__ Xb, float* __restrict__ sq,
    float* __restrict__ partials) {
  int tid = threadIdx.x;
  int lane32 = tid & 31;
  int rgrp = tid >> 5;
  int c = lane32 * 8;
  int rowBase = blockIdx.x * 32;

  float colpart[8];
#pragma unroll
  for (int j = 0; j < 8; ++j) colpart[j] = 0.f;

#pragma unroll
  for (int p = 0; p < 4; ++p) {
    int row = rowBase + p * 8 + rgrp;
    const float* X = (row < NHALF) ? (src + (size_t)row * DIM)
                                   : (tgt + (size_t)(row - NHALF) * DIM);
    float4 v0 = *(const float4*)(X + c);
    float4 v1 = *(const float4*)(X + c + 4);
    float vals[8] = {v0.x, v0.y, v0.z, v0.w, v1.x, v1.y, v1.z, v1.w};
    u16x8 h;
    float s = 0.f;
#pragma unroll
    for (int j = 0; j < 8; ++j) {
      unsigned short b = f2bf(vals[j]);
      h[j] = b;
      float rb = bf2f(b);
      s += rb * rb;
      colpart[j] += rb;
    }
    *(u16x8*)(Xb + (size_t)row * DIM + c) = h;
    for (int o = 16; o > 0; o >>= 1) s += __shfl_down(s, o, 32);
    if (lane32 == 0) sq[row] = s;
  }

  __shared__ float cp[8][DIM];
  *(float4*)&cp[rgrp][c]     = make_float4(colpart[0], colpart[1], colpart[2], colpart[3]);
  *(float4*)&cp[rgrp][c + 4] = make_float4(colpart[4], colpart[5], colpart[6], colpart[7]);
  __syncthreads();
  float s8 = 0.f;
#pragma unroll
  for (int r = 0; r < 8; ++r) s8 += cp[r][tid];
  partials[blockIdx.x * DIM + tid] = s8;
}

// ---- Kernel 2: reduce partials + sq -> bandwidth -> c0 (round-0 exact) ----
__global__ __launch_bounds__(256) void mmd_band(
    const float* __restrict__ partials, const float* __restrict__ sq,
    float* __restrict__ c0out) {
  __shared__ double buf2[DIM];
  __shared__ float buf1[DIM];
  int tid = threadIdx.x;
  float cs = 0.f;
  for (int b = 0; b < PREP_BLOCKS; ++b) cs += partials[b * DIM + tid];
  float s1 = 0.f;
  for (int k = 0; k < NS / DIM; ++k) s1 += sq[k * DIM + tid];
  buf2[tid] = (double)cs * (double)cs;
  buf1[tid] = s1;
  __syncthreads();
  for (int o = 128; o > 0; o >>= 1) {
    if (tid < o) { buf2[tid] += buf2[tid + o]; buf1[tid] += buf1[tid + o]; }
    __syncthreads();
  }
  if (tid == 0) {
    double S1 = (double)buf1[0];
    double S2 = buf2[0];
    double sum_l2 = 2.0 * (double)NS * S1 - 2.0 * S2;
    double bw = sum_l2 / ((double)NS * (double)NS - (double)NS);
    bw = bw / 4.0;
    c0out[0] = (float)(1.4426950408889634 / bw);
  }
}

// ---- Kernel 3: 128x128 Gram, BK=32 dbuf + COUNTED-vmcnt pipeline (T3+T4) ----
// r0-r6 lesson: every __syncthreads K-loop drains vmcnt(0) per kt (compiler
// barrier semantics), force-stalling all waves on the just-issued prefetch —
// that drain is the stable ~40% no-issue gap. Fix per T3/T4: raw s_barrier +
// counted s_waitcnt vmcnt(4) so the next tile's 4 loads/wave stay in flight
// across barriers; vmcnt(0) only at the last K-step. Each wave:
//   vmcnt(4) ; bar           <- buf[cur] staged by ALL waves
//   ds_read frags
//   lgkmcnt(0); sched_barrier(0)   <- rule #18 (MFMA hoist trap)
//   bar                       <- all waves done READING buf[cur]
//   STAGE(kt+2 -> buf[cur])   <- async overwrite, flies under MFMA
//   MFMA x16
// Epilogue sq/c0 loads issue in the prologue, USES deferred to epilogue so the
// compiler emits no early wait; at kt0, vmcnt(4) drains sq+S0 and leaves
// exactly S1 (4 insts) in flight.
#define STAGE(KT, BUF)                                                        \
  {                                                                           \
    _Pragma("unroll") for (int it = 0; it < 2; ++it) {                        \
      int idx = it * 256 + tid;            /* 0..511, 16B each */             \
      int r = idx >> 2, g = idx & 3;       /* row 0..127, 16B group 0..3 */   \
      int gs = g ^ ((r >> 1) & 3);         /* pre-swizzled SOURCE (rule 21)*/ \
      const unsigned short* ga =                                              \
          Xb + (size_t)(rowBase + r) * DIM + (KT)*BK + gs * 8;                \
      __builtin_amdgcn_global_load_lds(                                       \
          (const __attribute__((address_space(1))) void*)ga,                  \
          (__attribute__((address_space(3))) void*)(&As[BUF][idx * 8]), 16,   \
          0, 0);                                                              \
      const unsigned short* gb =                                              \
          Xb + (size_t)(colBase + r) * DIM + (KT)*BK + gs * 8;                \
      __builtin_amdgcn_global_load_lds(                                       \
          (const __attribute__((address_space(1))) void*)gb,                  \
          (__attribute__((address_space(3))) void*)(&Bs[BUF][idx * 8]), 16,   \
          0, 0);                                                              \
    }                                                                         \
  }

__global__ __launch_bounds__(256, 2) void mmd_gram(
    const unsigned short* __restrict__ Xb, const float* __restrict__ sq,
    const float* __restrict__ c0p, double* __restrict__ accK) {
  int l = blockIdx.x;
  int bj = (int)((sqrtf(8.f * (float)l + 1.f) - 1.f) * 0.5f);
  while ((bj + 1) * (bj + 2) / 2 <= l) bj++;
  while (bj * (bj + 1) / 2 > l) bj--;
  int bi = l - bj * (bj + 1) / 2;

  __shared__ __align__(16) unsigned short As[2][BLK * BK];  // 16 KiB
  __shared__ __align__(16) unsigned short Bs[2][BLK * BK];  // 16 KiB
  int tid = threadIdx.x;
  int wave = tid >> 6;
  int lane = tid & 63;
  int rowBase = bi * BLK, colBase = bj * BLK;
  int wr = (wave >> 1) * 64;   // wave's 64x64 quadrant
  int wc = (wave & 1) * 64;

  // prologue loads: issue now, USED only in the epilogue (no early wait)
  float c0v = *c0p;
  float sqr[4][4], sqc[4];
  int r4 = (lane >> 4) * 4;
#pragma unroll
  for (int m = 0; m < 4; ++m)
#pragma unroll
    for (int r = 0; r < 4; ++r)
      sqr[m][r] = sq[rowBase + wr + m * 16 + r4 + r];
#pragma unroll
  for (int n = 0; n < 4; ++n)
    sqc[n] = sq[colBase + wc + n * 16 + (lane & 15)];

  f32x4 acc[4][4];
#pragma unroll
  for (int m = 0; m < 4; ++m)
#pragma unroll
    for (int n = 0; n < 4; ++n) acc[m][n] = (f32x4){0.f, 0.f, 0.f, 0.f};

  // prologue: two K-steps in flight before the loop
  STAGE(0, 0);
  STAGE(1, 1);

#pragma unroll
  for (int kt = 0; kt < NKT; ++kt) {
    int cur = kt & 1;
    // my stage(kt) loads done; stage(kt+1)'s 4 insts may remain in flight
    if (kt == NKT - 1)
      asm volatile("s_waitcnt vmcnt(0)" ::: "memory");
    else
      asm volatile("s_waitcnt vmcnt(4)" ::: "memory");
    __builtin_amdgcn_s_barrier();      // buf[cur] staged by all waves

    bf16x8 af[4], bfr[4];
    int kg = lane >> 4;                // 16B k-group 0..3 of this lane
#pragma unroll
    for (int m = 0; m < 4; ++m) {
      int r = wr + m * 16 + (lane & 15);
      af[m] = *(const bf16x8*)(&As[cur][r * BK + (kg ^ ((r >> 1) & 3)) * 8]);
    }
#pragma unroll
    for (int n = 0; n < 4; ++n) {
      int r = wc + n * 16 + (lane & 15);
      bfr[n] = *(const bf16x8*)(&Bs[cur][r * BK + (kg ^ ((r >> 1) & 3)) * 8]);
    }
    asm volatile("s_waitcnt lgkmcnt(0)" ::: "memory");
    __builtin_amdgcn_sched_barrier(0);   // rule #18: keep MFMA below the wait
    __builtin_amdgcn_s_barrier();        // all waves done reading buf[cur]

    if (kt < NKT - 2) STAGE(kt + 2, cur);  // async overwrite, flies under MFMA

#pragma unroll
    for (int m = 0; m < 4; ++m)
#pragma unroll
      for (int n = 0; n < 4; ++n)
        acc[m][n] = __builtin_amdgcn_mfma_f32_16x16x32_bf16(
            af[m], bfr[n], acc[m][n], 0, 0, 0);
  }

  // ---- epilogue: l2 -> sum of 5 Gaussians (1 exp2 + 4 squarings) ----
  float cE = -0.0625f * c0v;     // arg = cE*(sqr+sqc) + t2*acc
  float t2 = -2.f * cE;
  float a_[4][4], b_[4];
#pragma unroll
  for (int m = 0; m < 4; ++m)
#pragma unroll
    for (int r = 0; r < 4; ++r) a_[m][r] = cE * sqr[m][r];
#pragma unroll
  for (int n = 0; n < 4; ++n) b_[n] = cE * sqc[n];

  float tsum = 0.f;
#pragma unroll
  for (int m = 0; m < 4; ++m)
#pragma unroll
    for (int n = 0; n < 4; ++n)
#pragma unroll
      for (int r = 0; r < 4; ++r) {
        // C/D layout (m89): col = lane&15, row = (lane>>4)*4 + reg
        float arg = fmaf(acc[m][n][r], t2, a_[m][r] + b_[n]);
        float e4 = exp2f(arg);           // e_{k-1} = e_k^2
        float e3 = e4 * e4;
        float e2 = e3 * e3;
        float e1 = e2 * e2;
        float e0 = e1 * e1;
        tsum += ((e4 + e3) + (e2 + e1)) + e0;
      }

  // wave-level shuffle reduce, then tiny cross-wave combine.
  // As is dead after the K-loop (last frag reads barrier-ordered) -> reuse.
  float* red4 = (float*)&As[0][0];
#pragma unroll
  for (int o = 32; o > 0; o >>= 1) tsum += __shfl_down(tsum, o);
  if (lane == 0) red4[wave] = tsum;
  __syncthreads();
  if (tid == 0) {
    float t = (red4[0] + red4[1]) + (red4[2] + red4[3]);
    float sign = ((bi < HALF_TILES) == (bj < HALF_TILES)) ? 1.f : -1.f;
    float factor = (bi == bj) ? sign : 2.f * sign;  // off-diag tiles doubled
    atomicAdd(accK, (double)(factor * t));
  }
}

// ---- Kernel 4: finalize (round-0 exact) ----
__global__ void mmd_final(const double* __restrict__ accK, float* __restrict__ out) {
  out[0] = (float)(accK[0] / ((double)NHALF * (double)NHALF));
}

extern "C" void kernel_launch(void* const* d_in, const int* in_sizes, int n_in,
                              void* d_out, int out_size, void* d_ws, size_t ws_size,
                              hipStream_t stream) {
  if (ws_size < (size_t)WS_NEED) return;  // need ~4.3 MiB scratch
  const float* src = (const float*)d_in[0];
  const float* tgt = (const float*)d_in[1];
  char* ws = (char*)d_ws;
  unsigned short* Xb = (unsigned short*)(ws + XB_OFF);
  float* sq          = (float*)(ws + SQ_OFF);
  float* partials    = (float*)(ws + PART_OFF);
  double* accK       = (double*)(ws + ACC_OFF);
  float* c0          = (float*)(ws + C0_OFF);

  hipMemsetAsync(ws + ACC_OFF, 0, 16, stream);  // accK only
  mmd_prep<<<PREP_BLOCKS, 256, 0, stream>>>(src, tgt, Xb, sq, partials);
  mmd_band<<<1, 256, 0, stream>>>(partials, sq, c0);
  mmd_gram<<<NTRI, 256, 0, stream>>>(Xb, sq, c0, accK);
  mmd_final<<<1, 1, 0, stream>>>(accK, (float*)d_out);
}

// Round 8
// 66.804 us; speedup vs baseline: 1.0762x; 1.0212x over previous
//
#include <hip/hip_runtime.h>
#include <hip/hip_bf16.h>
#include <stdint.h>

#define NS 8192
#define NHALF 4096
#define DIM 256
#define BLK 128
#define BK 32
#define NKT (DIM / BK)           // 8 K-steps per tile
#define NTILES (NS / BLK)        // 64
#define HALF_TILES (NHALF / BLK) // 32
// column strips of up to 4 tiles: sum_{bj=0..63} ceil((bj+1)/4) = 544
#define NSTRIPS 544
#define PREP_BLOCKS 256

typedef __attribute__((ext_vector_type(8))) short bf16x8;
typedef __attribute__((ext_vector_type(4))) float f32x4;
typedef __attribute__((ext_vector_type(8))) unsigned short u16x8;

// workspace layout (bytes) — round-0 proven layout
#define XB_OFF   0                         // bf16 X: 8192*256*2 = 4 MiB
#define SQ_OFF   (NS * DIM * 2)            // f32 sq[8192] = 32 KiB
#define PART_OFF (SQ_OFF + NS * 4)         // f32 partials[256][256] = 256 KiB
#define ACC_OFF  (PART_OFF + PREP_BLOCKS * DIM * 4)  // f64 signed kernel sum
#define C0_OFF   (ACC_OFF + 8)             // f32 log2e / bandwidth
#define WS_NEED  (C0_OFF + 16)

__device__ __forceinline__ unsigned short f2bf(float f) {
  unsigned int u = __float_as_uint(f);
  u += 0x7fffu + ((u >> 16) & 1u);   // round-to-nearest-even
  return (unsigned short)(u >> 16);
}
__device__ __forceinline__ float bf2f(unsigned short h) {
  return __uint_as_float(((unsigned int)h) << 16);
}

// ---- Kernel 1: convert to bf16, row ||x||^2, per-block column partials ----
// (round-0 exact + block 0 zeroes accK, replacing the hipMemsetAsync dispatch)
__global__ __launch_bounds__(256) void mmd_prep(
    const float* __restrict__ src, const float* __restrict__ tgt,
    unsigned short* __restrict__ Xb, float* __restrict__ sq,
    float* __restrict__ partials, double* __restrict__ accK) {
  int tid = threadIdx.x;
  if (blockIdx.x == 0 && tid == 0) accK[0] = 0.0;   // stream-ordered before gram
  int lane32 = tid & 31;
  int rgrp = tid >> 5;
  int c = lane32 * 8;
  int rowBase = blockIdx.x * 32;

  float colpart[8];
#pragma unroll
  for (int j = 0; j < 8; ++j) colpart[j] = 0.f;

#pragma unroll
  for (int p = 0; p < 4; ++p) {
    int row = rowBase + p * 8 + rgrp;
    const float* X = (row < NHALF) ? (src + (size_t)row * DIM)
                                   : (tgt + (size_t)(row - NHALF) * DIM);
    float4 v0 = *(const float4*)(X + c);
    float4 v1 = *(const float4*)(X + c + 4);
    float vals[8] = {v0.x, v0.y, v0.z, v0.w, v1.x, v1.y, v1.z, v1.w};
    u16x8 h;
    float s = 0.f;
#pragma unroll
    for (int j = 0; j < 8; ++j) {
      unsigned short b = f2bf(vals[j]);
      h[j] = b;
      float rb = bf2f(b);
      s += rb * rb;
      colpart[j] += rb;
    }
    *(u16x8*)(Xb + (size_t)row * DIM + c) = h;
    for (int o = 16; o > 0; o >>= 1) s += __shfl_down(s, o, 32);
    if (lane32 == 0) sq[row] = s;
  }

  __shared__ float cp[8][DIM];
  *(float4*)&cp[rgrp][c]     = make_float4(colpart[0], colpart[1], colpart[2], colpart[3]);
  *(float4*)&cp[rgrp][c + 4] = make_float4(colpart[4], colpart[5], colpart[6], colpart[7]);
  __syncthreads();
  float s8 = 0.f;
#pragma unroll
  for (int r = 0; r < 8; ++r) s8 += cp[r][tid];
  partials[blockIdx.x * DIM + tid] = s8;
}

// ---- Kernel 2: bandwidth reduce, widened (1024 thr, 4-way b-split) ----
// r0 version did 256 serial strided loads in one 256-thread block (~latency
// bound). 4-way split -> 64 serial rounds; sq summed via float4.
__global__ __launch_bounds__(1024) void mmd_band(
    const float* __restrict__ partials, const float* __restrict__ sq,
    float* __restrict__ c0out) {
  __shared__ float CS[4][DIM];
  __shared__ float L1[1024];
  __shared__ double D2[DIM];
  int tid = threadIdx.x;
  int q = tid >> 8, col = tid & 255;
  float cs = 0.f;
  for (int b = 0; b < PREP_BLOCKS / 4; ++b)
    cs += partials[(q * 64 + b) * DIM + col];
  CS[q][col] = cs;
  const float4* s4 = (const float4*)sq;    // 2048 float4
  float4 va = s4[tid * 2], vb = s4[tid * 2 + 1];
  L1[tid] = (va.x + va.y + va.z + va.w) + (vb.x + vb.y + vb.z + vb.w);
  __syncthreads();
  if (tid < DIM) {
    float ctot = (CS[0][tid] + CS[1][tid]) + (CS[2][tid] + CS[3][tid]);
    D2[tid] = (double)ctot * (double)ctot;
    L1[tid] = (L1[tid] + L1[tid + 256]) + (L1[tid + 512] + L1[tid + 768]);
  }
  __syncthreads();
  for (int o = 128; o > 0; o >>= 1) {
    if (tid < o) { D2[tid] += D2[tid + o]; L1[tid] += L1[tid + o]; }
    __syncthreads();
  }
  if (tid == 0) {
    double S1 = (double)L1[0];
    double S2 = D2[0];
    double sum_l2 = 2.0 * (double)NS * S1 - 2.0 * S2;
    double bw = sum_l2 / ((double)NS * (double)NS - (double)NS);
    bw = bw / 4.0;
    c0out[0] = (float)(1.4426950408889634 / bw);
  }
}

// ---- Kernel 3: STRIP gram — up to 4 tiles (fixed bj, consecutive bi) per
// block, one continuous counted-vmcnt pipeline over 8*T K-steps ----
// r0-r7 lesson: all K-loop sync variants land 45-50 µs; the invariant is
// per-block fixed overhead (decode+prologue+epilogue+drain ~= 50% of block
// lifetime at K-depth 8) x 2080 blocks. Strips amortize it 3.8x and keep
// loads flying THROUGH the exp2 epilogue: tile t+1's first two stages are
// issued at tile t's kt=6/7, before the epilogue. vmcnt(0) only at the very
// last step. Next tile's sq-row loads interleave at kt==1; the vmcnt(4)
// bookkeeping stays correct under any issue order (waits are monotone;
// stage(s) always has >=2 intervening vmcnt(4) waits before its use-top).
#define STAGE(RB, KT, BUF)                                                    \
  {                                                                           \
    _Pragma("unroll") for (int it = 0; it < 2; ++it) {                        \
      int idx = it * 256 + tid;            /* 0..511, 16B each */             \
      int r = idx >> 2, g = idx & 3;       /* row 0..127, 16B group 0..3 */   \
      int gs = g ^ ((r >> 1) & 3);         /* pre-swizzled SOURCE (rule 21)*/ \
      const unsigned short* ga =                                              \
          Xb + (size_t)((RB) + r) * DIM + (KT)*BK + gs * 8;                   \
      __builtin_amdgcn_global_load_lds(                                       \
          (const __attribute__((address_space(1))) void*)ga,                  \
          (__attribute__((address_space(3))) void*)(&As[BUF][idx * 8]), 16,   \
          0, 0);                                                              \
      const unsigned short* gb =                                              \
          Xb + (size_t)(colBase + r) * DIM + (KT)*BK + gs * 8;                \
      __builtin_amdgcn_global_load_lds(                                       \
          (const __attribute__((address_space(1))) void*)gb,                  \
          (__attribute__((address_space(3))) void*)(&Bs[BUF][idx * 8]), 16,   \
          0, 0);                                                              \
    }                                                                         \
  }

__global__ __launch_bounds__(256, 2) void mmd_gram(
    const unsigned short* __restrict__ Xb, const float* __restrict__ sq,
    const float* __restrict__ c0p, double* __restrict__ accK) {
  // strip decode: C(bj) = strips in columns < bj = 2m(m+1)+j(m+1), bj=4m+j
  int S = blockIdx.x;
  int m0 = (int)sqrtf((float)S * 0.5f);
  if (m0 > 16) m0 = 16;
  int bj = 4 * m0;
  int C = 2 * m0 * (m0 + 1);
  while (C > S) { bj--; C -= (bj >> 2) + 1; }
  while (C + ((bj >> 2) + 1) <= S) { C += (bj >> 2) + 1; bj++; }
  int sIdx = S - C;              // strip index within column bj
  int bi0 = 4 * sIdx;            // first tile row of this strip
  int T = bj - bi0 + 1; if (T > 4) T = 4;   // tiles in this strip

  __shared__ __align__(16) unsigned short As[2][BLK * BK];  // 16 KiB
  __shared__ __align__(16) unsigned short Bs[2][BLK * BK];  // 16 KiB
  int tid = threadIdx.x;
  int wave = tid >> 6;
  int lane = tid & 63;
  int colBase = bj * BLK;
  int wr = (wave >> 1) * 64;   // wave's 64x64 quadrant
  int wc = (wave & 1) * 64;

  // prologue loads (used later; drained by the pipeline's counted waits)
  float c0v = *c0p;
  int r4 = (lane >> 4) * 4;
  f32x4 sqrC[4], sqrN[4];
#pragma unroll
  for (int m = 0; m < 4; ++m)
    sqrC[m] = *(const f32x4*)&sq[bi0 * BLK + wr + m * 16 + r4];
  float sqc[4];
#pragma unroll
  for (int n = 0; n < 4; ++n) sqc[n] = sq[colBase + wc + n * 16 + (lane & 15)];

  float cE = -0.0625f * c0v;     // arg = cE*(sqr+sqc) + t2*acc
  float t2 = -2.f * cE;
  float b_[4];
#pragma unroll
  for (int n = 0; n < 4; ++n) b_[n] = cE * sqc[n];

  f32x4 acc[4][4];
  float tsum = 0.f;              // signed, accumulated across tiles

  // pipeline prologue: 2 K-steps in flight
  STAGE(bi0 * BLK, 0, 0);
  STAGE(bi0 * BLK, 1, 1);

  for (int t = 0; t < T; ++t) {
    int rowBase = (bi0 + t) * BLK;
    int rowBaseN = rowBase + BLK;
    bool hasNext = (t + 1 < T);
#pragma unroll
    for (int m = 0; m < 4; ++m)
#pragma unroll
      for (int n = 0; n < 4; ++n) acc[m][n] = (f32x4){0.f, 0.f, 0.f, 0.f};

#pragma unroll
    for (int kt = 0; kt < NKT; ++kt) {
      // wait for stage(this step); keep 1 stage (4 insts) in flight,
      // except at the block's very last step.
      if (kt == NKT - 1 && t == T - 1)
        asm volatile("s_waitcnt vmcnt(0)" ::: "memory");
      else
        asm volatile("s_waitcnt vmcnt(4)" ::: "memory");
      __builtin_amdgcn_s_barrier();      // buf[kt&1] staged by all waves

      bf16x8 af[4], bfr[4];
      int cur = kt & 1;
      int kg = lane >> 4;                // 16B k-group 0..3 of this lane
#pragma unroll
      for (int m = 0; m < 4; ++m) {
        int r = wr + m * 16 + (lane & 15);
        af[m] = *(const bf16x8*)(&As[cur][r * BK + (kg ^ ((r >> 1) & 3)) * 8]);
      }
#pragma unroll
      for (int n = 0; n < 4; ++n) {
        int r = wc + n * 16 + (lane & 15);
        bfr[n] = *(const bf16x8*)(&Bs[cur][r * BK + (kg ^ ((r >> 1) & 3)) * 8]);
      }
      asm volatile("s_waitcnt lgkmcnt(0)" ::: "memory");
      __builtin_amdgcn_sched_barrier(0);   // rule #18: keep MFMA below wait
      __builtin_amdgcn_s_barrier();        // all waves done reading buf[cur]

      // next tile's epilogue row-sq loads, interleaved mid-pipeline
      if (kt == 1 && hasNext) {
#pragma unroll
        for (int m = 0; m < 4; ++m)
          sqrN[m] = *(const f32x4*)&sq[rowBaseN + wr + m * 16 + r4];
      }
      // stage step s+2 (crosses into next tile at kt=6,7)
      if (kt <= 5) { STAGE(rowBase, kt + 2, cur); }
      else if (hasNext) {
        if (kt == 6) { STAGE(rowBaseN, 0, 0); }
        else         { STAGE(rowBaseN, 1, 1); }
      }

#pragma unroll
      for (int m = 0; m < 4; ++m)
#pragma unroll
        for (int n = 0; n < 4; ++n)
          acc[m][n] = __builtin_amdgcn_mfma_f32_16x16x32_bf16(
              af[m], bfr[n], acc[m][n], 0, 0, 0);
    }  // kt

    // ---- per-tile epilogue (pure VALU; next tile's stages are in flight) --
    int bi = bi0 + t;
    float a_[4][4];
#pragma unroll
    for (int m = 0; m < 4; ++m)
#pragma unroll
      for (int r = 0; r < 4; ++r) a_[m][r] = cE * sqrC[m][r];
    float part = 0.f;
#pragma unroll
    for (int m = 0; m < 4; ++m)
#pragma unroll
      for (int n = 0; n < 4; ++n)
#pragma unroll
        for (int r = 0; r < 4; ++r) {
          // C/D layout (m89): col = lane&15, row = (lane>>4)*4 + reg
          float arg = fmaf(acc[m][n][r], t2, a_[m][r] + b_[n]);
          float e4 = exp2f(arg);           // e_{k-1} = e_k^2
          float e3 = e4 * e4;
          float e2 = e3 * e3;
          float e1 = e2 * e2;
          float e0 = e1 * e1;
          part += ((e4 + e3) + (e2 + e1)) + e0;
        }
    float sign = ((bi < HALF_TILES) == (bj < HALF_TILES)) ? 1.f : -1.f;
    float factor = (bi == bj) ? sign : 2.f * sign;  // off-diag doubled
    tsum = fmaf(factor, part, tsum);
#pragma unroll
    for (int m = 0; m < 4; ++m) sqrC[m] = sqrN[m];   // shift next -> current
  }  // t

  // one cross-wave reduce + one atomic per STRIP (was per tile).
  // As is dead (all reads barrier-ordered into registers) -> reuse.
  float* red4 = (float*)&As[0][0];
#pragma unroll
  for (int o = 32; o > 0; o >>= 1) tsum += __shfl_down(tsum, o);
  if (lane == 0) red4[wave] = tsum;
  __syncthreads();
  if (tid == 0) {
    float tt = (red4[0] + red4[1]) + (red4[2] + red4[3]);
    atomicAdd(accK, (double)tt);
  }
}

// ---- Kernel 4: finalize (round-0 exact) ----
__global__ void mmd_final(const double* __restrict__ accK, float* __restrict__ out) {
  out[0] = (float)(accK[0] / ((double)NHALF * (double)NHALF));
}

extern "C" void kernel_launch(void* const* d_in, const int* in_sizes, int n_in,
                              void* d_out, int out_size, void* d_ws, size_t ws_size,
                              hipStream_t stream) {
  if (ws_size < (size_t)WS_NEED) return;  // need ~4.3 MiB scratch
  const float* src = (const float*)d_in[0];
  const float* tgt = (const float*)d_in[1];
  char* ws = (char*)d_ws;
  unsigned short* Xb = (unsigned short*)(ws + XB_OFF);
  float* sq          = (float*)(ws + SQ_OFF);
  float* partials    = (float*)(ws + PART_OFF);
  double* accK       = (double*)(ws + ACC_OFF);
  float* c0          = (float*)(ws + C0_OFF);

  mmd_prep<<<PREP_BLOCKS, 256, 0, stream>>>(src, tgt, Xb, sq, partials, accK);
  mmd_band<<<1, 1024, 0, stream>>>(partials, sq, c0);
  mmd_gram<<<NSTRIPS, 256, 0, stream>>>(Xb, sq, c0, accK);
  mmd_final<<<1, 1, 0, stream>>>(accK, (float*)d_out);
}

// Round 9
// 59.062 us; speedup vs baseline: 1.2173x; 1.1311x over previous
//
#include <hip/hip_runtime.h>
#include <hip/hip_bf16.h>
#include <stdint.h>

#define NS 8192
#define NHALF 4096
#define DIM 256
#define BLK 128
#define BK 32
#define NKT (DIM / BK)           // 8 K-steps
#define NTILES (NS / BLK)        // 64
#define HALF_TILES (NHALF / BLK) // 32
#define NTRI (NTILES * (NTILES + 1) / 2)  // 2080 upper-tri tiles
#define PREP_BLOCKS 256

typedef __attribute__((ext_vector_type(8))) short bf16x8;
typedef __attribute__((ext_vector_type(4))) float f32x4;
typedef __attribute__((ext_vector_type(8))) unsigned short u16x8;

// workspace layout (bytes) — round-0 proven layout
#define XB_OFF   0                         // bf16 X: 8192*256*2 = 4 MiB
#define SQ_OFF   (NS * DIM * 2)            // f32 sq[8192] = 32 KiB
#define PART_OFF (SQ_OFF + NS * 4)         // f32 partials[256][256] = 256 KiB
#define ACC_OFF  (PART_OFF + PREP_BLOCKS * DIM * 4)  // f64 signed kernel sum
#define C0_OFF   (ACC_OFF + 8)             // f32 log2e / bandwidth
#define WS_NEED  (C0_OFF + 16)

__device__ __forceinline__ unsigned short f2bf(float f) {
  unsigned int u = __float_as_uint(f);
  u += 0x7fffu + ((u >> 16) & 1u);   // round-to-nearest-even
  return (unsigned short)(u >> 16);
}
__device__ __forceinline__ float bf2f(unsigned short h) {
  return __uint_as_float(((unsigned int)h) << 16);
}

// ---- Kernel 1: convert to bf16, row ||x||^2, per-block column partials ----
// (round-0 exact + block 0 zeroes accK, replacing the hipMemsetAsync dispatch)
__global__ __launch_bounds__(256) void mmd_prep(
    const float* __restrict__ src, const float* __restrict__ tgt,
    unsigned short* __restrict__ Xb, float* __restrict__ sq,
    float* __restrict__ partials, double* __restrict__ accK) {
  int tid = threadIdx.x;
  if (blockIdx.x == 0 && tid == 0) accK[0] = 0.0;   // stream-ordered before gram
  int lane32 = tid & 31;
  int rgrp = tid >> 5;
  int c = lane32 * 8;
  int rowBase = blockIdx.x * 32;

  float colpart[8];
#pragma unroll
  for (int j = 0; j < 8; ++j) colpart[j] = 0.f;

#pragma unroll
  for (int p = 0; p < 4; ++p) {
    int row = rowBase + p * 8 + rgrp;
    const float* X = (row < NHALF) ? (src + (size_t)row * DIM)
                                   : (tgt + (size_t)(row - NHALF) * DIM);
    float4 v0 = *(const float4*)(X + c);
    float4 v1 = *(const float4*)(X + c + 4);
    float vals[8] = {v0.x, v0.y, v0.z, v0.w, v1.x, v1.y, v1.z, v1.w};
    u16x8 h;
    float s = 0.f;
#pragma unroll
    for (int j = 0; j < 8; ++j) {
      unsigned short b = f2bf(vals[j]);
      h[j] = b;
      float rb = bf2f(b);
      s += rb * rb;
      colpart[j] += rb;
    }
    *(u16x8*)(Xb + (size_t)row * DIM + c) = h;
    for (int o = 16; o > 0; o >>= 1) s += __shfl_down(s, o, 32);
    if (lane32 == 0) sq[row] = s;
  }

  __shared__ float cp[8][DIM];
  *(float4*)&cp[rgrp][c]     = make_float4(colpart[0], colpart[1], colpart[2], colpart[3]);
  *(float4*)&cp[rgrp][c + 4] = make_float4(colpart[4], colpart[5], colpart[6], colpart[7]);
  __syncthreads();
  float s8 = 0.f;
#pragma unroll
  for (int r = 0; r < 8; ++r) s8 += cp[r][tid];
  partials[blockIdx.x * DIM + tid] = s8;
}

// ---- Kernel 2: bandwidth reduce, widened (1024 thr, 4-way b-split) ----
// (round-8 exact, verified)
__global__ __launch_bounds__(1024) void mmd_band(
    const float* __restrict__ partials, const float* __restrict__ sq,
    float* __restrict__ c0out) {
  __shared__ float CS[4][DIM];
  __shared__ float L1[1024];
  __shared__ double D2[DIM];
  int tid = threadIdx.x;
  int q = tid >> 8, col = tid & 255;
  float cs = 0.f;
  for (int b = 0; b < PREP_BLOCKS / 4; ++b)
    cs += partials[(q * 64 + b) * DIM + col];
  CS[q][col] = cs;
  const float4* s4 = (const float4*)sq;    // 2048 float4
  float4 va = s4[tid * 2], vb = s4[tid * 2 + 1];
  L1[tid] = (va.x + va.y + va.z + va.w) + (vb.x + vb.y + vb.z + vb.w);
  __syncthreads();
  if (tid < DIM) {
    float ctot = (CS[0][tid] + CS[1][tid]) + (CS[2][tid] + CS[3][tid]);
    D2[tid] = (double)ctot * (double)ctot;
    L1[tid] = (L1[tid] + L1[tid + 256]) + (L1[tid + 512] + L1[tid + 768]);
  }
  __syncthreads();
  for (int o = 128; o > 0; o >>= 1) {
    if (tid < o) { D2[tid] += D2[tid + o]; L1[tid] += L1[tid + o]; }
    __syncthreads();
  }
  if (tid == 0) {
    double S1 = (double)L1[0];
    double S2 = D2[0];
    double sum_l2 = 2.0 * (double)NS * S1 - 2.0 * S2;
    double bw = sum_l2 / ((double)NS * (double)NS - (double)NS);
    bw = bw / 4.0;
    c0out[0] = (float)(1.4426950408889634 / bw);
  }
}

// ---- Kernel 3: 128x128 Gram, TRIPLE-buffered counted-vmcnt pipeline ----
// r7 structure (best gram: 47.4 µs) with the second per-kt barrier removed.
// 3 LDS buffers: stage(kt+2) writes buf[(kt+2)%3] == buf[(kt-1)%3], whose
// readers all drained (their lgkmcnt(0) precedes barrier(kt), which every
// wave passed). So the WAR-protection barrier is unnecessary: ONE barrier
// per K-step (9/block vs r7's 17). LDS = 48 KiB -> still 2 blocks/CU under
// the measured 128-KiB pool (r5: 64-KiB blocks never pair).
// Per wave, per kt:
//   vmcnt(4) [last kt: 0]  <- my stage(kt) loads done (stage(kt+1) in flight)
//   s_barrier              <- all waves' stage(kt) done
//   ds_read frags(buf[kt%3]); lgkmcnt(0); sched_barrier(0)   (rule #18)
//   STAGE(kt+2 -> buf[(kt+2)%3])    <- flies under MFMA
//   MFMA x16
#define STAGE(KT, BUF)                                                        \
  {                                                                           \
    _Pragma("unroll") for (int it = 0; it < 2; ++it) {                        \
      int idx = it * 256 + tid;            /* 0..511, 16B each */             \
      int r = idx >> 2, g = idx & 3;       /* row 0..127, 16B group 0..3 */   \
      int gs = g ^ ((r >> 1) & 3);         /* pre-swizzled SOURCE (rule 21)*/ \
      const unsigned short* ga =                                              \
          Xb + (size_t)(rowBase + r) * DIM + (KT)*BK + gs * 8;                \
      __builtin_amdgcn_global_load_lds(                                       \
          (const __attribute__((address_space(1))) void*)ga,                  \
          (__attribute__((address_space(3))) void*)(&As[BUF][idx * 8]), 16,   \
          0, 0);                                                              \
      const unsigned short* gb =                                              \
          Xb + (size_t)(colBase + r) * DIM + (KT)*BK + gs * 8;                \
      __builtin_amdgcn_global_load_lds(                                       \
          (const __attribute__((address_space(1))) void*)gb,                  \
          (__attribute__((address_space(3))) void*)(&Bs[BUF][idx * 8]), 16,   \
          0, 0);                                                              \
    }                                                                         \
  }

__global__ __launch_bounds__(256, 2) void mmd_gram(
    const unsigned short* __restrict__ Xb, const float* __restrict__ sq,
    const float* __restrict__ c0p, double* __restrict__ accK) {
  int l = blockIdx.x;
  int bj = (int)((sqrtf(8.f * (float)l + 1.f) - 1.f) * 0.5f);
  while ((bj + 1) * (bj + 2) / 2 <= l) bj++;
  while (bj * (bj + 1) / 2 > l) bj--;
  int bi = l - bj * (bj + 1) / 2;

  __shared__ __align__(16) unsigned short As[3][BLK * BK];  // 24 KiB
  __shared__ __align__(16) unsigned short Bs[3][BLK * BK];  // 24 KiB
  int tid = threadIdx.x;
  int wave = tid >> 6;
  int lane = tid & 63;
  int rowBase = bi * BLK, colBase = bj * BLK;
  int wr = (wave >> 1) * 64;   // wave's 64x64 quadrant
  int wc = (wave & 1) * 64;

  // prologue loads: issue now, USED only in the epilogue (no early wait);
  // kt0's vmcnt(4) drains them together with stage(0).
  float c0v = *c0p;
  float sqr[4][4], sqc[4];
  int r4 = (lane >> 4) * 4;
#pragma unroll
  for (int m = 0; m < 4; ++m)
#pragma unroll
    for (int r = 0; r < 4; ++r)
      sqr[m][r] = sq[rowBase + wr + m * 16 + r4 + r];
#pragma unroll
  for (int n = 0; n < 4; ++n)
    sqc[n] = sq[colBase + wc + n * 16 + (lane & 15)];

  f32x4 acc[4][4];
#pragma unroll
  for (int m = 0; m < 4; ++m)
#pragma unroll
    for (int n = 0; n < 4; ++n) acc[m][n] = (f32x4){0.f, 0.f, 0.f, 0.f};

  // pipeline prologue: two K-steps in flight
  STAGE(0, 0);
  STAGE(1, 1);

#pragma unroll
  for (int kt = 0; kt < NKT; ++kt) {
    int cur = kt % 3;
    // my stage(kt) loads done; stage(kt+1)'s 4 insts may remain in flight
    if (kt == NKT - 1)
      asm volatile("s_waitcnt vmcnt(0)" ::: "memory");
    else
      asm volatile("s_waitcnt vmcnt(4)" ::: "memory");
    __builtin_amdgcn_s_barrier();      // buf[cur] staged by all waves

    bf16x8 af[4], bfr[4];
    int kg = lane >> 4;                // 16B k-group 0..3 of this lane
#pragma unroll
    for (int m = 0; m < 4; ++m) {
      int r = wr + m * 16 + (lane & 15);
      af[m] = *(const bf16x8*)(&As[cur][r * BK + (kg ^ ((r >> 1) & 3)) * 8]);
    }
#pragma unroll
    for (int n = 0; n < 4; ++n) {
      int r = wc + n * 16 + (lane & 15);
      bfr[n] = *(const bf16x8*)(&Bs[cur][r * BK + (kg ^ ((r >> 1) & 3)) * 8]);
    }
    asm volatile("s_waitcnt lgkmcnt(0)" ::: "memory");
    __builtin_amdgcn_sched_barrier(0);   // rule #18: keep MFMA below the wait

    // overwrite buf[(kt+2)%3] == buf[(kt-1)%3]: all its readers drained
    // before barrier(kt) -> no second barrier needed (triple buffer).
    if (kt < NKT - 2) STAGE(kt + 2, (kt + 2) % 3);

#pragma unroll
    for (int m = 0; m < 4; ++m)
#pragma unroll
      for (int n = 0; n < 4; ++n)
        acc[m][n] = __builtin_amdgcn_mfma_f32_16x16x32_bf16(
            af[m], bfr[n], acc[m][n], 0, 0, 0);
  }

  // ---- epilogue: l2 -> sum of 5 Gaussians (1 exp2 + 4 squarings) ----
  float cE = -0.0625f * c0v;     // arg = cE*(sqr+sqc) + t2*acc
  float t2 = -2.f * cE;
  float a_[4][4], b_[4];
#pragma unroll
  for (int m = 0; m < 4; ++m)
#pragma unroll
    for (int r = 0; r < 4; ++r) a_[m][r] = cE * sqr[m][r];
#pragma unroll
  for (int n = 0; n < 4; ++n) b_[n] = cE * sqc[n];

  float tsum = 0.f;
#pragma unroll
  for (int m = 0; m < 4; ++m)
#pragma unroll
    for (int n = 0; n < 4; ++n)
#pragma unroll
      for (int r = 0; r < 4; ++r) {
        // C/D layout (m89): col = lane&15, row = (lane>>4)*4 + reg
        float arg = fmaf(acc[m][n][r], t2, a_[m][r] + b_[n]);
        float e4 = exp2f(arg);           // e_{k-1} = e_k^2
        float e3 = e4 * e4;
        float e2 = e3 * e3;
        float e1 = e2 * e2;
        float e0 = e1 * e1;
        tsum += ((e4 + e3) + (e2 + e1)) + e0;
      }

  // wave-level shuffle reduce, then tiny cross-wave combine.
  // As[0] (buf 0) last read at kt=6; all waves passed barrier(7) -> safe.
  float* red4 = (float*)&As[0][0];
#pragma unroll
  for (int o = 32; o > 0; o >>= 1) tsum += __shfl_down(tsum, o);
  if (lane == 0) red4[wave] = tsum;
  __syncthreads();
  if (tid == 0) {
    float t = (red4[0] + red4[1]) + (red4[2] + red4[3]);
    float sign = ((bi < HALF_TILES) == (bj < HALF_TILES)) ? 1.f : -1.f;
    float factor = (bi == bj) ? sign : 2.f * sign;  // off-diag tiles doubled
    atomicAdd(accK, (double)(factor * t));
  }
}

// ---- Kernel 4: finalize (round-0 exact) ----
__global__ void mmd_final(const double* __restrict__ accK, float* __restrict__ out) {
  out[0] = (float)(accK[0] / ((double)NHALF * (double)NHALF));
}

extern "C" void kernel_launch(void* const* d_in, const int* in_sizes, int n_in,
                              void* d_out, int out_size, void* d_ws, size_t ws_size,
                              hipStream_t stream) {
  if (ws_size < (size_t)WS_NEED) return;  // need ~4.3 MiB scratch
  const float* src = (const float*)d_in[0];
  const float* tgt = (const float*)d_in[1];
  char* ws = (char*)d_ws;
  unsigned short* Xb = (unsigned short*)(ws + XB_OFF);
  float* sq          = (float*)(ws + SQ_OFF);
  float* partials    = (float*)(ws + PART_OFF);
  double* accK       = (double*)(ws + ACC_OFF);
  float* c0          = (float*)(ws + C0_OFF);

  mmd_prep<<<PREP_BLOCKS, 256, 0, stream>>>(src, tgt, Xb, sq, partials, accK);
  mmd_band<<<1, 1024, 0, stream>>>(partials, sq, c0);
  mmd_gram<<<NTRI, 256, 0, stream>>>(Xb, sq, c0, accK);
  mmd_final<<<1, 1, 0, stream>>>(accK, (float*)d_out);
}